// Round 5
// baseline (7931.871 us; speedup 1.0000x reference)
//
#include <hip/hip_runtime.h>
#include <hip/hip_bf16.h>

#define Bsz 32
#define Ssz 128
#define Tsz 64
#define TD  63           // decoder steps
#define NSTEP 191        // Ssz + TD
#define Esz 128
#define Hsz 256
#define G4  1024         // 4*H
#define Vsz 32000

typedef __attribute__((ext_vector_type(8))) short short8;
typedef __attribute__((ext_vector_type(4))) float f32x4;

__device__ __forceinline__ unsigned short f2bf(float f) {
    union { float f; unsigned u; } v; v.f = f;
    unsigned u = v.u;
    unsigned r = u + 0x7FFFu + ((u >> 16) & 1u);   // RNE
    return (unsigned short)(r >> 16);
}

__device__ __forceinline__ float rcpf(float x) { return __builtin_amdgcn_rcpf(x); }
__device__ __forceinline__ float sigm(float x) { return rcpf(1.f + __expf(-x)); }
// tanh(x) = 1 - 2/(e^{2x}+1); saturates correctly at +-inf
__device__ __forceinline__ float tanh_fast(float x) { return 1.f - 2.f * rcpf(1.f + __expf(2.f * x)); }

// ---------------------------------------------------------------------------
// K0: convert Wfc fp32 -> bf16 in workspace
// ---------------------------------------------------------------------------
__global__ void k_cvt(const float* __restrict__ src, unsigned short* __restrict__ dst, long n) {
    long i = (long)blockIdx.x * blockDim.x + threadIdx.x;
    long base = i * 8;
    if (base >= n) return;
    float4 f0 = ((const float4*)(src + base))[0];
    float4 f1 = ((const float4*)(src + base))[1];
    union { unsigned short u[8]; uint4 v; } r;
    r.u[0] = f2bf(f0.x); r.u[1] = f2bf(f0.y); r.u[2] = f2bf(f0.z); r.u[3] = f2bf(f0.w);
    r.u[4] = f2bf(f1.x); r.u[5] = f2bf(f1.y); r.u[6] = f2bf(f1.z); r.u[7] = f2bf(f1.w);
    *(uint4*)(dst + base) = r.v;
}

// ---------------------------------------------------------------------------
// K0b: pack Whh_e/Whh_d into per-fragment bf16 layout for k_recur's
// gate-major MFMA. Fragment id t = (w*4+mt)*2*8*... :
//   t = ((((w*4 + mt)*2 + mat)*8 + kt)*64 + l), each thread emits 8 bf16.
//   lane l: n16 = l&15 (A-row within tile), q = l>>4 (k-slice).
//   Packed A row n16 = 4*hcq + g  ->  Whh row = g*256 + (16w + 4mt + hcq).
// ---------------------------------------------------------------------------
__global__ void k_pack(const float* __restrict__ Whh_e, const float* __restrict__ Whh_d,
                       unsigned short* __restrict__ W2) {
    int t = blockIdx.x * 256 + threadIdx.x;     // 0..65535
    int l   = t & 63;
    int kt  = (t >> 6) & 7;
    int mat = (t >> 9) & 1;
    int mt  = (t >> 10) & 3;
    int w   = t >> 12;                           // 0..15
    int n16 = l & 15, qq = l >> 4;
    int g = n16 & 3, hcq = n16 >> 2;
    int row = g * 256 + 16 * w + 4 * mt + hcq;
    const float* src = (mat ? Whh_d : Whh_e) + (long)row * Hsz + kt * 32 + qq * 8;
    union { unsigned short u[8]; uint4 v; } r;
    #pragma unroll
    for (int e = 0; e < 8; ++e) r.u[e] = f2bf(src[e]);
    ((uint4*)W2)[t] = r.v;
}

// ---------------------------------------------------------------------------
// K1: xW2 = emb[token(t,b)] @ Wih^T + bias for all 191 steps, written in the
// THREAD-MAJOR layout k_recur's single block consumes:
//   float index = ((t*1024 + w*64 + L)*8 + (mt*2 + nt))*4 + gate
// where the (w,L,mt,nt) cell owns (batch = 16nt + (L&15), h-col = 16w+4mt+(L>>4)).
// grid (16, 191) as before; per-thread writes are scattered dwords (as before).
// ---------------------------------------------------------------------------
__global__ void __launch_bounds__(256) k_input(
        const int* __restrict__ src, const int* __restrict__ trg,
        const float* __restrict__ emb_src, const float* __restrict__ emb_trg,
        const float* __restrict__ Wih_e, const float* __restrict__ Wih_d,
        const float* __restrict__ b_e, const float* __restrict__ b_d,
        float* __restrict__ xW) {
    const int t = blockIdx.y;
    const int nb = blockIdx.x;
    const int tid = threadIdx.x;
    const bool enc = (t < Ssz);
    const float* emb  = enc ? emb_src : emb_trg;
    const float* Wih  = enc ? Wih_e : Wih_d;
    const float* bias = enc ? b_e : b_d;

    __shared__ unsigned short a_lds[32][Esz + 8];   // [32][136] bf16

    {   // stage embedding rows (bf16) for the 32 batch elements
        int b = tid >> 3, seg = tid & 7;
        int tok = enc ? src[b * Ssz + t] : trg[b * Tsz + (t - Ssz)];
        const float* row = emb + (long)tok * Esz + seg * 16;
        #pragma unroll
        for (int i = 0; i < 16; ++i)
            a_lds[b][seg * 16 + i] = f2bf(row[i]);
    }
    __syncthreads();

    const int w = tid >> 6, l = tid & 63;
    const int n = l & 15, q = l >> 4;
    const int col = nb * 64 + w * 16 + n;           // 0..1023

    short8 bw[4];
    #pragma unroll
    for (int kt = 0; kt < 4; ++kt) {
        const float* wr = Wih + (long)col * Esz + kt * 32 + q * 8;
        short8 f;
        #pragma unroll
        for (int i = 0; i < 8; ++i) f[i] = (short)f2bf(wr[i]);
        bw[kt] = f;
    }
    f32x4 acc0 = {0.f,0.f,0.f,0.f}, acc1 = {0.f,0.f,0.f,0.f};
    #pragma unroll
    for (int kt = 0; kt < 4; ++kt) {
        int k0 = kt * 32 + q * 8;
        short8 a0 = *(const short8*)&a_lds[n][k0];
        short8 a1 = *(const short8*)&a_lds[16 + n][k0];
        acc0 = __builtin_amdgcn_mfma_f32_16x16x32_bf16(a0, bw[kt], acc0, 0, 0, 0);
        acc1 = __builtin_amdgcn_mfma_f32_16x16x32_bf16(a1, bw[kt], acc1, 0, 0, 0);
    }
    float bv = bias[col];
    // remap (batch, col) -> thread-major xW2 layout
    const int g = col >> 8, hc = col & 255;
    const int W = hc >> 4, mt4 = (hc >> 2) & 3, qq2 = hc & 3;
    float* o = xW + (long)t * 32768;
    #pragma unroll
    for (int r = 0; r < 4; ++r) {
        int m = q * 4 + r;
        {   // batch m (nt = 0)
            int L = qq2 * 16 + m;
            o[((W * 64 + L) * 8 + (mt4 * 2 + 0)) * 4 + g] = acc0[r] + bv;
        }
        {   // batch 16+m (nt = 1)
            int L = qq2 * 16 + m;
            o[((W * 64 + L) * 8 + (mt4 * 2 + 1)) * 4 + g] = acc1[r] + bv;
        }
    }
}

// ---------------------------------------------------------------------------
// K2: LSTM recurrence — SINGLE BLOCK (1024 threads, one CU), fully local.
//
// After r0-r4 established that every cross-block h-exchange protocol costs
// multiple L3 RTTs + poll contention per step (~4600cy of the 6600cy step),
// this version eliminates inter-block communication entirely:
//   * h lives ONLY in LDS (double-buffered [2][32][264] bf16, 33KB);
//     ONE __syncthreads per step, no atomics, no sentinels, no spins.
//   * GATE-MAJOR MFMA: C[gate-row][batch] with Whh rows packed as 4*hc+g
//     (k_pack). Lane (n,q) of wave w, tile (mt,nt) holds in its 4 acc regs
//     exactly gates i,f,g,o of (batch 16nt+n, h-col 16w+4mt+q) -> pointwise
//     runs DIRECTLY on MFMA output registers. No gate transpose at all.
//   * Weights resident in VGPRs: 64 fragments x 16B x 2 mats = 256 VGPR/wave;
//     16 waves hold the full 1MB packed Whh pair. Loaded once from W2.
//   * xW prefetched one step ahead (8 dwordx4/thread from thread-major xW2).
//   * LDS h store XOR-swizzled at 16B granularity (unit ^= b&7) so the
//     stride-528B rows don't alias banks on ds_read_b128.
// Per-step: ~1080cy MFMA + ~2560cy transcendentals + ~2500cy LDS reads,
// overlapped across 16 waves / 3 pipes -> ~3000-3500cy ≈ 1.3µs.
// ---------------------------------------------------------------------------
__global__ void __launch_bounds__(1024, 1) k_recur(
        const unsigned short* __restrict__ W2,
        const float* __restrict__ xW2,
        unsigned short* __restrict__ hsu,          // [63][32][256] bf16
        float* __restrict__ out_tail) {
    const int tid = threadIdx.x;
    const int w = tid >> 6, l = tid & 63;
    const int n = l & 15, q = l >> 4;
    const int a3 = n & 7;                          // = b&7 for both nt halves

    __shared__ unsigned short h_lds[2][32][Hsz + 8];   // row = 528 B = 33 units

    {   // zero both buffers (h_0 = 0); 8448 dwords
        unsigned* z = (unsigned*)&h_lds[0][0][0];
        #pragma unroll
        for (int i = 0; i < 9; ++i) {
            int idx = i * 1024 + tid;
            if (idx < 8448) z[idx] = 0u;
        }
    }

    // resident weight fragments (A operand, gate-major packing)
    short8 aw_e[4][8], aw_d[4][8];
    {
        const short8* wp = (const short8*)W2;
        #pragma unroll
        for (int mt = 0; mt < 4; ++mt)
            #pragma unroll
            for (int kt = 0; kt < 8; ++kt) {
                aw_e[mt][kt] = wp[(((w * 4 + mt) * 2 + 0) * 8 + kt) * 64 + l];
                aw_d[mt][kt] = wp[(((w * 4 + mt) * 2 + 1) * 8 + kt) * 64 + l];
            }
    }

    // xg prefetch (step 0) — 8 float4 = this thread's 8 cells x 4 gates
    const long xoff = (long)(w * 64 + l) * 32;
    float4 xgv[8];
    #pragma unroll
    for (int j = 0; j < 8; ++j) xgv[j] = ((const float4*)(xW2 + xoff))[j];

    float cst[8];
    #pragma unroll
    for (int j = 0; j < 8; ++j) cst[j] = 0.f;

    for (int s = 0; s < NSTEP; ++s) {
        __syncthreads();                           // h(s) complete in buf[s&1]

        // B-fragments: h[batch = 16nt+n][k] , 16 x ds_read_b128, swizzled
        const unsigned short (*hb)[Hsz + 8] = h_lds[s & 1];
        short8 bh[2][8];
        #pragma unroll
        for (int nt = 0; nt < 2; ++nt) {
            const char* rowb = (const char*)&hb[16 * nt + n][0];
            #pragma unroll
            for (int kt = 0; kt < 8; ++kt) {
                int u = ((4 * kt + q) ^ a3) << 4;
                bh[nt][kt] = *(const short8*)(rowb + u);
            }
        }

        f32x4 acc[4][2];
        #pragma unroll
        for (int mt = 0; mt < 4; ++mt) {
            acc[mt][0] = (f32x4){0.f, 0.f, 0.f, 0.f};
            acc[mt][1] = (f32x4){0.f, 0.f, 0.f, 0.f};
        }
        if (s < Ssz) {
            #pragma unroll
            for (int mt = 0; mt < 4; ++mt)
                #pragma unroll
                for (int nt = 0; nt < 2; ++nt)
                    #pragma unroll
                    for (int kt = 0; kt < 8; ++kt)
                        acc[mt][nt] = __builtin_amdgcn_mfma_f32_16x16x32_bf16(
                            aw_e[mt][kt], bh[nt][kt], acc[mt][nt], 0, 0, 0);
        } else {
            #pragma unroll
            for (int mt = 0; mt < 4; ++mt)
                #pragma unroll
                for (int nt = 0; nt < 2; ++nt)
                    #pragma unroll
                    for (int kt = 0; kt < 8; ++kt)
                        acc[mt][nt] = __builtin_amdgcn_mfma_f32_16x16x32_bf16(
                            aw_d[mt][kt], bh[nt][kt], acc[mt][nt], 0, 0, 0);
        }

        // pointwise directly on acc regs; write h(s+1) to the other buffer
        unsigned short (*hw)[Hsz + 8] = h_lds[(s + 1) & 1];
        #pragma unroll
        for (int mt = 0; mt < 4; ++mt) {
            #pragma unroll
            for (int nt = 0; nt < 2; ++nt) {
                const int j = mt * 2 + nt;
                float4 xg = xgv[j];
                float gi = acc[mt][nt][0] + xg.x;
                float gf = acc[mt][nt][1] + xg.y;
                float gg = acc[mt][nt][2] + xg.z;
                float go = acc[mt][nt][3] + xg.w;
                float c = sigm(gf) * cst[j] + sigm(gi) * tanh_fast(gg);
                cst[j] = c;
                float h = sigm(go) * tanh_fast(c);
                const int b  = 16 * nt + n;
                const int hc = 16 * w + 4 * mt + q;
                const int hi = (hc >> 3) ^ a3;     // swizzled 16B unit
                unsigned short hbf = f2bf(h);
                *(unsigned short*)((char*)&hw[b][0] + hi * 16 + (hc & 7) * 2) = hbf;
                if (s >= Ssz)
                    hsu[((long)(s - Ssz) * Bsz + b) * Hsz + hc] = hbf;
                if (s == NSTEP - 1) {
                    out_tail[b * Hsz + hc] = h;
                    out_tail[Bsz * Hsz + b * Hsz + hc] = c;
                }
            }
        }

        // prefetch xg for step s+1 (overlaps barrier + next MFMA phase)
        {
            const int sn = (s + 1 < NSTEP) ? s + 1 : NSTEP - 1;
            const float* xb = xW2 + (long)sn * 32768 + xoff;
            #pragma unroll
            for (int j = 0; j < 8; ++j) xgv[j] = ((const float4*)xb)[j];
        }
    }
}

// ---------------------------------------------------------------------------
// K3: projection out[b][td+1][v] = hs[td][b][:] @ Wfc[v][:] + bfc[v]
// grid (125, 9): x = 256-col slice of V, y = group of 7 decoder steps.
// B tile (128KB) staged ONCE per block and reused for 7 steps (r5 change:
// was re-staged 63x -> ~1GB of L3 reads; now 144MB).
// ---------------------------------------------------------------------------
__global__ void __launch_bounds__(256) k_proj(
        const unsigned short* __restrict__ hs, const unsigned short* __restrict__ WfcB,
        const float* __restrict__ bfc, float* __restrict__ out) {
    const int vb = blockIdx.x;    // 0..124
    const int tid = threadIdx.x, w = tid >> 6, l = tid & 63, n = l & 15, q = l >> 4;

    __shared__ unsigned short a_lds[32][Hsz + 8];     // 16.5 KB
    __shared__ unsigned short b_lds[256][Hsz + 8];    // 132 KB

    {   // stage B tile: 128 KB contiguous from WfcB, remapped into padded rows
        const uint4* g = (const uint4*)(WfcB + (long)vb * 256 * Hsz);
        #pragma unroll 4
        for (int i = 0; i < 32; ++i) {
            int u = i * 256 + tid;           // uint4 index (8 bf16 each)
            int row = u >> 5;
            int kk = (u & 31) * 8;
            *(uint4*)&b_lds[row][kk] = g[u];
        }
    }

    for (int tdi = 0; tdi < 7; ++tdi) {
        const int td = blockIdx.y * 7 + tdi;
        if (tdi > 0) __syncthreads();   // previous iteration's a_lds reads done
        {   // stage A: hs rows for this td (contiguous 16 KB)
            int b = tid >> 3, seg = tid & 7;
            const uint4* g = (const uint4*)(hs + ((long)td * Bsz + b) * Hsz);
            #pragma unroll
            for (int i = 0; i < 4; ++i)
                *(uint4*)&a_lds[b][i * 64 + seg * 8] = g[i * 8 + seg];
        }
        __syncthreads();                 // A (and, first iter, B) staged

        short8 af[2][8];
        #pragma unroll
        for (int kt = 0; kt < 8; ++kt) {
            int k0 = kt * 32 + q * 8;
            af[0][kt] = *(const short8*)&a_lds[n][k0];
            af[1][kt] = *(const short8*)&a_lds[16 + n][k0];
        }
        f32x4 acc[2][4];
        #pragma unroll
        for (int nt = 0; nt < 4; ++nt) {
            acc[0][nt] = (f32x4){0.f,0.f,0.f,0.f};
            acc[1][nt] = (f32x4){0.f,0.f,0.f,0.f};
        }
        #pragma unroll
        for (int nt = 0; nt < 4; ++nt) {
            int cl = w * 64 + nt * 16 + n;
            #pragma unroll
            for (int kt = 0; kt < 8; ++kt) {
                short8 bf = *(const short8*)&b_lds[cl][kt * 32 + q * 8];
                acc[0][nt] = __builtin_amdgcn_mfma_f32_16x16x32_bf16(af[0][kt], bf, acc[0][nt], 0, 0, 0);
                acc[1][nt] = __builtin_amdgcn_mfma_f32_16x16x32_bf16(af[1][kt], bf, acc[1][nt], 0, 0, 0);
            }
        }
        #pragma unroll
        for (int nt = 0; nt < 4; ++nt) {
            int col = vb * 256 + w * 64 + nt * 16 + n;
            float bv = bfc[col];
            #pragma unroll
            for (int mt = 0; mt < 2; ++mt) {
                #pragma unroll
                for (int r = 0; r < 4; ++r) {
                    int b = mt * 16 + q * 4 + r;
                    out[(long)b * (Tsz * Vsz) + (long)(td + 1) * Vsz + col] = acc[mt][nt][r] + bv;
                }
            }
        }
    }
}

// ---------------------------------------------------------------------------
// K4: zero prediction slot t=0 (d_out is poisoned before every launch)
// ---------------------------------------------------------------------------
__global__ void k_zero0(float* __restrict__ out) {
    int i = blockIdx.x * 256 + threadIdx.x;    // 256000 float4s = 32*32000 floats
    int b = i / 8000;
    int c = i % 8000;
    ((float4*)(out + (long)b * (Tsz * Vsz)))[c] = make_float4(0.f, 0.f, 0.f, 0.f);
}

// ---------------------------------------------------------------------------
extern "C" void kernel_launch(void* const* d_in, const int* in_sizes, int n_in,
                              void* d_out, int out_size, void* d_ws, size_t ws_size,
                              hipStream_t stream) {
    const int*   src     = (const int*)d_in[0];
    const int*   trg     = (const int*)d_in[1];
    const float* emb_src = (const float*)d_in[2];
    const float* Wih_e   = (const float*)d_in[3];
    const float* Whh_e   = (const float*)d_in[4];
    const float* b_e     = (const float*)d_in[5];
    const float* emb_trg = (const float*)d_in[6];
    const float* Wih_d   = (const float*)d_in[7];
    const float* Whh_d   = (const float*)d_in[8];
    const float* b_d     = (const float*)d_in[9];
    const float* Wfc     = (const float*)d_in[10];
    const float* bfc     = (const float*)d_in[11];
    float* out = (float*)d_out;

    char* ws = (char*)d_ws;
    float*          xW2  = (float*)ws;                          // 191*32768*4 = 25,034,752 B
    unsigned short* WfcB = (unsigned short*)(ws + 25034752);    // 32000*256*2 = 16,384,000 B
    unsigned short* hs   = (unsigned short*)(ws + 41418752);    // 63*32*256*2 =  1,032,192 B
    unsigned short* W2   = (unsigned short*)(ws + 42450944);    // packed Whh  =  1,048,576 B
    (void)ws_size;

    k_cvt<<<4000, 256, 0, stream>>>(Wfc, WfcB, 8192000L);
    k_pack<<<256, 256, 0, stream>>>(Whh_e, Whh_d, W2);
    k_input<<<dim3(16, 191), 256, 0, stream>>>(src, trg, emb_src, emb_trg,
                                               Wih_e, Wih_d, b_e, b_d, xW2);
    k_recur<<<1, 1024, 0, stream>>>(W2, xW2, hs, out + 65536000L);
    k_zero0<<<1000, 256, 0, stream>>>(out);
    k_proj<<<dim3(125, 9), 256, 0, stream>>>(hs, WfcB, bfc, out);
}

// Round 6
// 1972.140 us; speedup vs baseline: 4.0220x; 4.0220x over previous
//
#include <hip/hip_runtime.h>
#include <hip/hip_bf16.h>

#define Bsz 32
#define Ssz 128
#define Tsz 64
#define TD  63           // decoder steps
#define NSTEP 191        // Ssz + TD
#define Esz 128
#define Hsz 256
#define G4  1024         // 4*H
#define Vsz 32000
#define NB  4            // recurrence blocks (4 CUs)
#define SENT32 0xFFC1FFC1u   // 2x bf16 NaN — unreachable as packed h pair

typedef __attribute__((ext_vector_type(8))) short short8;
typedef __attribute__((ext_vector_type(4))) float f32x4;

__device__ __forceinline__ unsigned short f2bf(float f) {
    union { float f; unsigned u; } v; v.f = f;
    unsigned u = v.u;
    unsigned r = u + 0x7FFFu + ((u >> 16) & 1u);   // RNE
    return (unsigned short)(r >> 16);
}

__device__ __forceinline__ float rcpf(float x) { return __builtin_amdgcn_rcpf(x); }
__device__ __forceinline__ float sigm(float x) { return rcpf(1.f + __expf(-x)); }
// tanh(x) = 1 - 2/(e^{2x}+1); saturates correctly at +-inf
__device__ __forceinline__ float tanh_fast(float x) { return 1.f - 2.f * rcpf(1.f + __expf(2.f * x)); }

__device__ __forceinline__ bool has_sent(unsigned long long v) {
    return ((unsigned)v == SENT32) || ((unsigned)(v >> 32) == SENT32);
}

// ---------------------------------------------------------------------------
// K0: convert Wfc fp32 -> bf16 in workspace
// ---------------------------------------------------------------------------
__global__ void k_cvt(const float* __restrict__ src, unsigned short* __restrict__ dst, long n) {
    long i = (long)blockIdx.x * blockDim.x + threadIdx.x;
    long base = i * 8;
    if (base >= n) return;
    float4 f0 = ((const float4*)(src + base))[0];
    float4 f1 = ((const float4*)(src + base))[1];
    union { unsigned short u[8]; uint4 v; } r;
    r.u[0] = f2bf(f0.x); r.u[1] = f2bf(f0.y); r.u[2] = f2bf(f0.z); r.u[3] = f2bf(f0.w);
    r.u[4] = f2bf(f1.x); r.u[5] = f2bf(f1.y); r.u[6] = f2bf(f1.z); r.u[7] = f2bf(f1.w);
    *(uint4*)(dst + base) = r.v;
}

// ---------------------------------------------------------------------------
// K0b: pack Whh_e/Whh_d into per-fragment bf16 layout for k_recur.
// Fragment f = (((nb*16 + mtt)*2 + mat)*8 + kt)*64 + l; lane l: n16=l&15,
// qq=l>>4; packed A-row n16 = 4*hcq + g -> Whh row g*256 + nb*64 + 4*mtt + hcq.
// (r5-verified mapping, re-based from 16-tiles-per-wave to 4-block split.)
// ---------------------------------------------------------------------------
__global__ void k_pack(const float* __restrict__ Whh_e, const float* __restrict__ Whh_d,
                       unsigned short* __restrict__ W2) {
    int f = blockIdx.x * 256 + threadIdx.x;      // 0..65535
    int l   = f & 63;
    int kt  = (f >> 6) & 7;
    int mat = (f >> 9) & 1;
    int mtt = (f >> 10) & 15;
    int nb  = f >> 14;                            // 0..3
    int n16 = l & 15, qq = l >> 4;
    int g = n16 & 3, hcq = n16 >> 2;
    int row = g * 256 + nb * 64 + 4 * mtt + hcq;
    const float* src = (mat ? Whh_d : Whh_e) + (long)row * Hsz + kt * 32 + qq * 8;
    union { unsigned short u[8]; uint4 v; } r;
    #pragma unroll
    for (int e = 0; e < 8; ++e) r.u[e] = f2bf(src[e]);
    ((uint4*)W2)[f] = r.v;
}

// ---------------------------------------------------------------------------
// K1: xW2 = emb[token(t,b)] @ Wih^T + bias, thread-major for k_recur's 4
// blocks: float idx = ((t*4 + nb)*1024 + tid)*8 + mt2*4 + g, where thread
// (nb, w=nt*8+w7, l=q*16+n) cell mt2 owns (batch 16nt+n, hcol 64nb+4*(2w7+mt2)+q).
// Also initializes hbuf: slot 0 = h_0 zeros, slots 1..191 = SENTINEL.
// ---------------------------------------------------------------------------
__global__ void __launch_bounds__(256) k_input(
        const int* __restrict__ src, const int* __restrict__ trg,
        const float* __restrict__ emb_src, const float* __restrict__ emb_trg,
        const float* __restrict__ Wih_e, const float* __restrict__ Wih_d,
        const float* __restrict__ b_e, const float* __restrict__ b_d,
        float* __restrict__ xW, unsigned* __restrict__ hbuf_dw) {
    const int t = blockIdx.y;
    const int nb = blockIdx.x;
    const int tid = threadIdx.x;
    const bool enc = (t < Ssz);
    const float* emb  = enc ? emb_src : emb_trg;
    const float* Wih  = enc ? Wih_e : Wih_d;
    const float* bias = enc ? b_e : b_d;

    __shared__ unsigned short a_lds[32][Esz + 8];   // [32][136] bf16

    {   // stage embedding rows (bf16) for the 32 batch elements
        int b = tid >> 3, seg = tid & 7;
        int tok = enc ? src[b * Ssz + t] : trg[b * Tsz + (t - Ssz)];
        const float* row = emb + (long)tok * Esz + seg * 16;
        #pragma unroll
        for (int i = 0; i < 16; ++i)
            a_lds[b][seg * 16 + i] = f2bf(row[i]);
    }
    // sentinel-fill slot t+1 (16 blocks x 256 threads = 4096 dwords = 1 slot)
    __hip_atomic_store(&hbuf_dw[(t + 1) * 4096 + nb * 256 + tid], SENT32,
                       __ATOMIC_RELAXED, __HIP_MEMORY_SCOPE_AGENT);
    if (t == 0) {   // slot 0 (h_0 = zeros)
        __hip_atomic_store(&hbuf_dw[nb * 256 + tid], 0u, __ATOMIC_RELAXED,
                           __HIP_MEMORY_SCOPE_AGENT);
    }
    __syncthreads();

    const int w = tid >> 6, l = tid & 63;
    const int n = l & 15, q = l >> 4;
    const int col = nb * 64 + w * 16 + n;           // gate-row 0..1023

    short8 bw[4];
    #pragma unroll
    for (int kt = 0; kt < 4; ++kt) {
        const float* wr = Wih + (long)col * Esz + kt * 32 + q * 8;
        short8 f;
        #pragma unroll
        for (int i = 0; i < 8; ++i) f[i] = (short)f2bf(wr[i]);
        bw[kt] = f;
    }
    f32x4 acc0 = {0.f,0.f,0.f,0.f}, acc1 = {0.f,0.f,0.f,0.f};
    #pragma unroll
    for (int kt = 0; kt < 4; ++kt) {
        int k0 = kt * 32 + q * 8;
        short8 a0 = *(const short8*)&a_lds[n][k0];
        short8 a1 = *(const short8*)&a_lds[16 + n][k0];
        acc0 = __builtin_amdgcn_mfma_f32_16x16x32_bf16(a0, bw[kt], acc0, 0, 0, 0);
        acc1 = __builtin_amdgcn_mfma_f32_16x16x32_bf16(a1, bw[kt], acc1, 0, 0, 0);
    }
    float bv = bias[col];
    // remap (gate-row col, batch) -> 4-block thread-major layout
    const int g = col >> 8, hc = col & 255;
    const int nbr = hc >> 6, c6 = hc & 63;
    const int mtt = c6 >> 2, qr = c6 & 3;
    const int w7 = mtt >> 1, mt2 = mtt & 1;
    float* o = xW + (long)t * 32768 + (long)nbr * 8192;
    #pragma unroll
    for (int r = 0; r < 4; ++r) {
        int m = q * 4 + r;      // batch (nt=0) / batch-16 (nt=1)
        o[((0 * 8 + w7) * 64 + qr * 16 + m) * 8 + mt2 * 4 + g] = acc0[r] + bv;
        o[((1 * 8 + w7) * 64 + qr * 16 + m) * 8 + mt2 * 4 + g] = acc1[r] + bv;
    }
}

// ---------------------------------------------------------------------------
// K2: LSTM recurrence — 4 blocks x 1024 threads. Gate-major MFMA (r5-verified
// math), weights VGPR-resident per phase (64 regs/wave; decoder reloaded at
// s==Ssz), pointwise directly on acc registers, h exchanged through the
// r4-proven sentinel-slot protocol with batched retry.
//
// r5 lesson baked in: 1 MB of weights cannot fit one CU's 512 KB VGPR file
// (silent scratch spill, 14x regression). 4 blocks x 1 phase = 64 VGPR/wave.
//
// Exchange: hbuf = 192 fresh 16 KB slots. Publish: lanes shfl-pack 4 bf16
// (cols 4mtt..+3 of batch bm) into one u64; q==0 lanes store 2 u64 each ->
// 4 KB/block/step, dwordx2 agent stores, no drain, no flags. Consume: 2
// u64/thread coalesced, batched sentinel retry (all pending re-issued per
// round => ~1 L3 RTT/round). Slots fresh -> no ABA; stores monotone -> no
// livelock. h_lds double-buffered -> ONE barrier per step.
// ---------------------------------------------------------------------------
__global__ void __launch_bounds__(1024, 1) k_recur(
        const unsigned short* __restrict__ W2,
        const float* __restrict__ xW2,
        unsigned* __restrict__ hbuf_dw,
        unsigned long long* __restrict__ hsu,      // [63][32][64] u64 history
        float* __restrict__ out_tail) {
    const int nb = blockIdx.x, tid = threadIdx.x;
    const int w = tid >> 6, l = tid & 63;
    const int n = l & 15, q = l >> 4;
    const int w7 = w & 7, nt = w >> 3;
    const int bm = nt * 16 + n;                    // this lane's batch (acc col)
    const int a3 = n & 7;

    __shared__ unsigned short h_lds[2][32][Hsz + 8];   // dbuf, row = 528 B

    const short8* wp = (const short8*)W2;
    short8 aw[2][8];                               // current-phase weights
    #pragma unroll
    for (int mt2 = 0; mt2 < 2; ++mt2) {
        const int mtt = 2 * w7 + mt2;
        #pragma unroll
        for (int kt = 0; kt < 8; ++kt)
            aw[mt2][kt] = wp[(((nb * 16 + mtt) * 2 + 0) * 8 + kt) * 64 + l];
    }

    float4 xg[2];
    {
        const float* xb = xW2 + (long)nb * 8192 + tid * 8;
        xg[0] = ((const float4*)xb)[0];
        xg[1] = ((const float4*)xb)[1];
    }
    float cst[2] = {0.f, 0.f};

    for (int s = 0; s < NSTEP; ++s) {
        // A: stage slot s -> h_lds[s&1]; 2 u64/thread, batched sentinel retry
        {
            const unsigned long long* hp =
                (const unsigned long long*)hbuf_dw + (long)s * 2048;
            char* const ldsb = (char*)&h_lds[s & 1][0][0];
            unsigned long long v0, v1;
            unsigned pend = 3u;
            do {
                if (pend & 1u)
                    v0 = __hip_atomic_load(hp + tid, __ATOMIC_RELAXED,
                                           __HIP_MEMORY_SCOPE_AGENT);
                if (pend & 2u)
                    v1 = __hip_atomic_load(hp + 1024 + tid, __ATOMIC_RELAXED,
                                           __HIP_MEMORY_SCOPE_AGENT);
                if ((pend & 1u) && !has_sent(v0)) {
                    int b = tid >> 6, j = tid & 63;   // row b, 8B unit j
                    *(unsigned long long*)(ldsb + b * 528 +
                        (((j >> 1) ^ (b & 7)) << 4) + (j & 1) * 8) = v0;
                    pend &= ~1u;
                }
                if ((pend & 2u) && !has_sent(v1)) {
                    int i = 1024 + tid, b = i >> 6, j = i & 63;
                    *(unsigned long long*)(ldsb + b * 528 +
                        (((j >> 1) ^ (b & 7)) << 4) + (j & 1) * 8) = v1;
                    pend &= ~2u;
                }
            } while (__builtin_expect(pend != 0, 0));
        }
        __syncthreads();   // ONLY barrier in the step (dbuf covers the rest)

        if (s == Ssz) {    // one-time switch to decoder weights
            #pragma unroll
            for (int mt2 = 0; mt2 < 2; ++mt2) {
                const int mtt = 2 * w7 + mt2;
                #pragma unroll
                for (int kt = 0; kt < 8; ++kt)
                    aw[mt2][kt] = wp[(((nb * 16 + mtt) * 2 + 1) * 8 + kt) * 64 + l];
            }
        }

        // B: MFMA — 2 A-tiles, K=256 as 4 chunks of 2 kt (bh streamed, 8 regs)
        const char* rowb = (const char*)&h_lds[s & 1][bm][0];
        f32x4 acc0 = {0.f,0.f,0.f,0.f}, acc1 = {0.f,0.f,0.f,0.f};
        #pragma unroll
        for (int hh = 0; hh < 4; ++hh) {
            short8 b0 = *(const short8*)(rowb + ((((8 * hh)     + q) ^ a3) << 4));
            short8 b1 = *(const short8*)(rowb + ((((8 * hh + 4) + q) ^ a3) << 4));
            acc0 = __builtin_amdgcn_mfma_f32_16x16x32_bf16(aw[0][2*hh],   b0, acc0, 0, 0, 0);
            acc1 = __builtin_amdgcn_mfma_f32_16x16x32_bf16(aw[1][2*hh],   b0, acc1, 0, 0, 0);
            acc0 = __builtin_amdgcn_mfma_f32_16x16x32_bf16(aw[0][2*hh+1], b1, acc0, 0, 0, 0);
            acc1 = __builtin_amdgcn_mfma_f32_16x16x32_bf16(aw[1][2*hh+1], b1, acc1, 0, 0, 0);
        }

        // C: pointwise on acc regs; shfl-pack 4 cols -> u64; q==0 publishes
        #pragma unroll
        for (int mt2 = 0; mt2 < 2; ++mt2) {
            const int mtt = 2 * w7 + mt2;
            const f32x4 a = mt2 ? acc1 : acc0;
            float gi = a[0] + xg[mt2].x;
            float gf = a[1] + xg[mt2].y;
            float gg = a[2] + xg[mt2].z;
            float go = a[3] + xg[mt2].w;
            float c = sigm(gf) * cst[mt2] + sigm(gi) * tanh_fast(gg);
            cst[mt2] = c;
            float h = sigm(go) * tanh_fast(c);

            unsigned pk = f2bf(h);                         // col 4mtt+q (u16)
            unsigned po = (unsigned)__shfl_xor((int)pk, 16);
            unsigned pair = (pk & 0xFFFFu) | (po << 16);   // cols (q, q+1), q even
            unsigned hi = (unsigned)__shfl_xor((int)pair, 32);
            if (q == 0) {
                unsigned long long u = (unsigned long long)pair
                                     | ((unsigned long long)hi << 32);
                __hip_atomic_store((unsigned long long*)hbuf_dw
                        + (long)(s + 1) * 2048 + bm * 64 + 16 * nb + mtt,
                        u, __ATOMIC_RELAXED, __HIP_MEMORY_SCOPE_AGENT);
                if (s >= Ssz)
                    hsu[((long)(s - Ssz) * Bsz + bm) * 64 + 16 * nb + mtt] = u;
            }
            if (s == NSTEP - 1) {
                const int hc = 64 * nb + 4 * mtt + q;
                out_tail[bm * Hsz + hc]             = h;
                out_tail[Bsz * Hsz + bm * Hsz + hc] = c;
            }
        }

        // D: prefetch next step's x-gates (overlaps next staging/poll)
        {
            const int sn = (s + 1 < NSTEP) ? s + 1 : s;
            const float* xb = xW2 + (long)sn * 32768 + (long)nb * 8192 + tid * 8;
            xg[0] = ((const float4*)xb)[0];
            xg[1] = ((const float4*)xb)[1];
        }
    }
}

// ---------------------------------------------------------------------------
// K3: projection out[b][td+1][v] = hs[td][b][:] @ Wfc[v][:] + bfc[v]
// grid (125, 9): x = 256-col slice of V, y = group of 7 decoder steps.
// B tile (128KB) staged ONCE per block, reused for 7 steps.
// ---------------------------------------------------------------------------
__global__ void __launch_bounds__(256) k_proj(
        const unsigned short* __restrict__ hs, const unsigned short* __restrict__ WfcB,
        const float* __restrict__ bfc, float* __restrict__ out) {
    const int vb = blockIdx.x;    // 0..124
    const int tid = threadIdx.x, w = tid >> 6, l = tid & 63, n = l & 15, q = l >> 4;

    __shared__ unsigned short a_lds[32][Hsz + 8];     // 16.5 KB
    __shared__ unsigned short b_lds[256][Hsz + 8];    // 132 KB

    {   // stage B tile: 128 KB contiguous from WfcB, remapped into padded rows
        const uint4* g = (const uint4*)(WfcB + (long)vb * 256 * Hsz);
        #pragma unroll 4
        for (int i = 0; i < 32; ++i) {
            int u = i * 256 + tid;           // uint4 index (8 bf16 each)
            int row = u >> 5;
            int kk = (u & 31) * 8;
            *(uint4*)&b_lds[row][kk] = g[u];
        }
    }

    for (int tdi = 0; tdi < 7; ++tdi) {
        const int td = blockIdx.y * 7 + tdi;
        if (tdi > 0) __syncthreads();   // previous iteration's a_lds reads done
        {   // stage A: hs rows for this td (contiguous 16 KB)
            int b = tid >> 3, seg = tid & 7;
            const uint4* g = (const uint4*)(hs + ((long)td * Bsz + b) * Hsz);
            #pragma unroll
            for (int i = 0; i < 4; ++i)
                *(uint4*)&a_lds[b][i * 64 + seg * 8] = g[i * 8 + seg];
        }
        __syncthreads();                 // A (and, first iter, B) staged

        short8 af[2][8];
        #pragma unroll
        for (int kt = 0; kt < 8; ++kt) {
            int k0 = kt * 32 + q * 8;
            af[0][kt] = *(const short8*)&a_lds[n][k0];
            af[1][kt] = *(const short8*)&a_lds[16 + n][k0];
        }
        f32x4 acc[2][4];
        #pragma unroll
        for (int nt = 0; nt < 4; ++nt) {
            acc[0][nt] = (f32x4){0.f,0.f,0.f,0.f};
            acc[1][nt] = (f32x4){0.f,0.f,0.f,0.f};
        }
        #pragma unroll
        for (int nt = 0; nt < 4; ++nt) {
            int cl = w * 64 + nt * 16 + n;
            #pragma unroll
            for (int kt = 0; kt < 8; ++kt) {
                short8 bf = *(const short8*)&b_lds[cl][kt * 32 + q * 8];
                acc[0][nt] = __builtin_amdgcn_mfma_f32_16x16x32_bf16(af[0][kt], bf, acc[0][nt], 0, 0, 0);
                acc[1][nt] = __builtin_amdgcn_mfma_f32_16x16x32_bf16(af[1][kt], bf, acc[1][nt], 0, 0, 0);
            }
        }
        #pragma unroll
        for (int nt = 0; nt < 4; ++nt) {
            int col = vb * 256 + w * 64 + nt * 16 + n;
            float bv = bfc[col];
            #pragma unroll
            for (int mt = 0; mt < 2; ++mt) {
                #pragma unroll
                for (int r = 0; r < 4; ++r) {
                    int b = mt * 16 + q * 4 + r;
                    out[(long)b * (Tsz * Vsz) + (long)(td + 1) * Vsz + col] = acc[mt][nt][r] + bv;
                }
            }
        }
    }
}

// ---------------------------------------------------------------------------
// K4: zero prediction slot t=0 (d_out is poisoned before every launch)
// ---------------------------------------------------------------------------
__global__ void k_zero0(float* __restrict__ out) {
    int i = blockIdx.x * 256 + threadIdx.x;    // 256000 float4s = 32*32000 floats
    int b = i / 8000;
    int c = i % 8000;
    ((float4*)(out + (long)b * (Tsz * Vsz)))[c] = make_float4(0.f, 0.f, 0.f, 0.f);
}

// ---------------------------------------------------------------------------
extern "C" void kernel_launch(void* const* d_in, const int* in_sizes, int n_in,
                              void* d_out, int out_size, void* d_ws, size_t ws_size,
                              hipStream_t stream) {
    const int*   src     = (const int*)d_in[0];
    const int*   trg     = (const int*)d_in[1];
    const float* emb_src = (const float*)d_in[2];
    const float* Wih_e   = (const float*)d_in[3];
    const float* Whh_e   = (const float*)d_in[4];
    const float* b_e     = (const float*)d_in[5];
    const float* emb_trg = (const float*)d_in[6];
    const float* Wih_d   = (const float*)d_in[7];
    const float* Whh_d   = (const float*)d_in[8];
    const float* b_d     = (const float*)d_in[9];
    const float* Wfc     = (const float*)d_in[10];
    const float* bfc     = (const float*)d_in[11];
    float* out = (float*)d_out;

    char* ws = (char*)d_ws;
    float*          xW2  = (float*)ws;                          // 191*32768*4 = 25,034,752 B
    unsigned short* WfcB = (unsigned short*)(ws + 25034752);    // 32000*256*2 = 16,384,000 B
    unsigned short* hs   = (unsigned short*)(ws + 41418752);    // 63*32*256*2 =  1,032,192 B
    unsigned short* W2   = (unsigned short*)(ws + 42450944);    // packed Whh  =  1,048,576 B
    unsigned*       hbuf = (unsigned*)(ws + 43499520);          // 192 slots x 16 KB = 3,145,728 B
    (void)ws_size;

    k_cvt<<<4000, 256, 0, stream>>>(Wfc, WfcB, 8192000L);
    k_pack<<<256, 256, 0, stream>>>(Whh_e, Whh_d, W2);
    k_input<<<dim3(16, 191), 256, 0, stream>>>(src, trg, emb_src, emb_trg,
                                               Wih_e, Wih_d, b_e, b_d, xW2, hbuf);
    k_recur<<<NB, 1024, 0, stream>>>(W2, xW2, hbuf,
                                     (unsigned long long*)hs, out + 65536000L);
    k_zero0<<<1000, 256, 0, stream>>>(out);
    k_proj<<<dim3(125, 9), 256, 0, stream>>>(hs, WfcB, bfc, out);
}

// Round 7
// 932.925 us; speedup vs baseline: 8.5022x; 2.1139x over previous
//
#include <hip/hip_runtime.h>
#include <hip/hip_bf16.h>

#define Bsz 32
#define Ssz 128
#define Tsz 64
#define TD  63           // decoder steps
#define NSTEP 191        // Ssz + TD
#define Esz 128
#define Hsz 256
#define G4  1024         // 4*H
#define Vsz 32000
#define NB  8            // recurrence blocks (8 CUs)
#define SENT32 0xFFC1FFC1u   // 2x bf16 NaN — unreachable as packed h pair

typedef __attribute__((ext_vector_type(8))) short short8;
typedef __attribute__((ext_vector_type(4))) float f32x4;

__device__ __forceinline__ unsigned short f2bf(float f) {
    union { float f; unsigned u; } v; v.f = f;
    unsigned u = v.u;
    unsigned r = u + 0x7FFFu + ((u >> 16) & 1u);   // RNE
    return (unsigned short)(r >> 16);
}

__device__ __forceinline__ float rcpf(float x) { return __builtin_amdgcn_rcpf(x); }
__device__ __forceinline__ float sigm(float x) { return rcpf(1.f + __expf(-x)); }
// tanh(x) = 1 - 2/(e^{2x}+1); saturates correctly at +-inf
__device__ __forceinline__ float tanh_fast(float x) { return 1.f - 2.f * rcpf(1.f + __expf(2.f * x)); }

__device__ __forceinline__ bool has_sent(unsigned long long v) {
    return ((unsigned)v == SENT32) || ((unsigned)(v >> 32) == SENT32);
}

// ---------------------------------------------------------------------------
// K0: convert Wfc fp32 -> bf16 in workspace
// ---------------------------------------------------------------------------
__global__ void k_cvt(const float* __restrict__ src, unsigned short* __restrict__ dst, long n) {
    long i = (long)blockIdx.x * blockDim.x + threadIdx.x;
    long base = i * 8;
    if (base >= n) return;
    float4 f0 = ((const float4*)(src + base))[0];
    float4 f1 = ((const float4*)(src + base))[1];
    union { unsigned short u[8]; uint4 v; } r;
    r.u[0] = f2bf(f0.x); r.u[1] = f2bf(f0.y); r.u[2] = f2bf(f0.z); r.u[3] = f2bf(f0.w);
    r.u[4] = f2bf(f1.x); r.u[5] = f2bf(f1.y); r.u[6] = f2bf(f1.z); r.u[7] = f2bf(f1.w);
    *(uint4*)(dst + base) = r.v;
}

// ---------------------------------------------------------------------------
// K0b: pack Whh_e/Whh_d into per-fragment bf16 layout for k_recur (8 blocks).
// Fragment f = (((nb*8 + mtt)*2 + mat)*8 + kt)*64 + l; lane l: n16=l&15,
// qq=l>>4; packed A-row n16 = 4*hcq + g -> Whh row g*256 + nb*32 + 4*mtt + hcq.
// (Gate-major mapping verified bit-exact in r5/r6.)
// ---------------------------------------------------------------------------
__global__ void k_pack(const float* __restrict__ Whh_e, const float* __restrict__ Whh_d,
                       unsigned short* __restrict__ W2) {
    int f = blockIdx.x * 256 + threadIdx.x;      // 0..65535
    int l   = f & 63;
    int kt  = (f >> 6) & 7;
    int mat = (f >> 9) & 1;
    int mtt = (f >> 10) & 7;
    int nb  = f >> 13;                            // 0..7
    int n16 = l & 15, qq = l >> 4;
    int g = n16 & 3, hcq = n16 >> 2;
    int row = g * 256 + nb * 32 + 4 * mtt + hcq;
    const float* src = (mat ? Whh_d : Whh_e) + (long)row * Hsz + kt * 32 + qq * 8;
    union { unsigned short u[8]; uint4 v; } r;
    #pragma unroll
    for (int e = 0; e < 8; ++e) r.u[e] = f2bf(src[e]);
    ((uint4*)W2)[f] = r.v;
}

// ---------------------------------------------------------------------------
// K1: xW2 = emb[token(t,b)] @ Wih^T + bias, thread-major for k_recur's 8
// blocks x 512 threads: float idx = ((t*8 + nb)*512 + tid)*8 + mt2*4 + g,
// where thread tid = (nt*4+w7)*64 + q*16 + n, cell mt2 owns
// (batch 16nt+n, hcol 32nb + 4*(2w7+mt2) + q).
// Also initializes hbuf: slot 0 = h_0 zeros, slots 1..191 = SENTINEL.
// ---------------------------------------------------------------------------
__global__ void __launch_bounds__(256) k_input(
        const int* __restrict__ src, const int* __restrict__ trg,
        const float* __restrict__ emb_src, const float* __restrict__ emb_trg,
        const float* __restrict__ Wih_e, const float* __restrict__ Wih_d,
        const float* __restrict__ b_e, const float* __restrict__ b_d,
        float* __restrict__ xW, unsigned* __restrict__ hbuf_dw) {
    const int t = blockIdx.y;
    const int nb = blockIdx.x;
    const int tid = threadIdx.x;
    const bool enc = (t < Ssz);
    const float* emb  = enc ? emb_src : emb_trg;
    const float* Wih  = enc ? Wih_e : Wih_d;
    const float* bias = enc ? b_e : b_d;

    __shared__ unsigned short a_lds[32][Esz + 8];   // [32][136] bf16

    {   // stage embedding rows (bf16) for the 32 batch elements
        int b = tid >> 3, seg = tid & 7;
        int tok = enc ? src[b * Ssz + t] : trg[b * Tsz + (t - Ssz)];
        const float* row = emb + (long)tok * Esz + seg * 16;
        #pragma unroll
        for (int i = 0; i < 16; ++i)
            a_lds[b][seg * 16 + i] = f2bf(row[i]);
    }
    // sentinel-fill slot t+1 (16 blocks x 256 threads = 4096 dwords = 1 slot)
    __hip_atomic_store(&hbuf_dw[(t + 1) * 4096 + nb * 256 + tid], SENT32,
                       __ATOMIC_RELAXED, __HIP_MEMORY_SCOPE_AGENT);
    if (t == 0) {   // slot 0 (h_0 = zeros)
        __hip_atomic_store(&hbuf_dw[nb * 256 + tid], 0u, __ATOMIC_RELAXED,
                           __HIP_MEMORY_SCOPE_AGENT);
    }
    __syncthreads();

    const int w = tid >> 6, l = tid & 63;
    const int n = l & 15, q = l >> 4;
    const int col = nb * 64 + w * 16 + n;           // gate-row 0..1023

    short8 bw[4];
    #pragma unroll
    for (int kt = 0; kt < 4; ++kt) {
        const float* wr = Wih + (long)col * Esz + kt * 32 + q * 8;
        short8 f;
        #pragma unroll
        for (int i = 0; i < 8; ++i) f[i] = (short)f2bf(wr[i]);
        bw[kt] = f;
    }
    f32x4 acc0 = {0.f,0.f,0.f,0.f}, acc1 = {0.f,0.f,0.f,0.f};
    #pragma unroll
    for (int kt = 0; kt < 4; ++kt) {
        int k0 = kt * 32 + q * 8;
        short8 a0 = *(const short8*)&a_lds[n][k0];
        short8 a1 = *(const short8*)&a_lds[16 + n][k0];
        acc0 = __builtin_amdgcn_mfma_f32_16x16x32_bf16(a0, bw[kt], acc0, 0, 0, 0);
        acc1 = __builtin_amdgcn_mfma_f32_16x16x32_bf16(a1, bw[kt], acc1, 0, 0, 0);
    }
    float bv = bias[col];
    // remap (gate-row col, batch) -> 8-block thread-major layout
    const int g = col >> 8, hc = col & 255;
    const int nbr = hc >> 5, c5 = hc & 31;
    const int mtt = c5 >> 2, qr = c5 & 3;
    const int w7 = mtt >> 1, mt2 = mtt & 1;
    float* o = xW + ((long)t * 8 + nbr) * 4096;     // 512 threads * 8 floats
    #pragma unroll
    for (int r = 0; r < 4; ++r) {
        int m = q * 4 + r;      // batch row within acc tile
        o[((0 * 4 + w7) * 64 + qr * 16 + m) * 8 + mt2 * 4 + g] = acc0[r] + bv;  // batch m
        o[((1 * 4 + w7) * 64 + qr * 16 + m) * 8 + mt2 * 4 + g] = acc1[r] + bv;  // batch 16+m
    }
}

// ---------------------------------------------------------------------------
// K2: LSTM recurrence — 8 blocks x 512 threads, gate-major MFMA, weights
// fully VGPR-resident (enc+dec = 128 VGPR/wave; cap 256 at 2 waves/SIMD via
// __launch_bounds__(512,2) -> no spill, the r6 failure mode).
//
// r6 lesson: 1024-thr blocks cap VGPR at 128 -> allocator spilled the 64-reg
// weight array to scratch (VGPR_Count=64, MFMA operands from scratch, 2.7x
// regression). 512-thr blocks double the cap; ~200 live regs fit.
//
// Exchange (r4-proven batched sentinel protocol): hbuf = 192 fresh 16 KB
// slots, u16 [slot][32][256]. Publish: lanes shfl-pack 4 cols into ONE u64
// store (no tearing) -> 2 KB/block/step, no drain, no flags. Consume: 4
// u64/thread coalesced, batched retry (all pending reissued per round ->
// ~1 L3 RTT/round). Slots fresh -> no ABA; stores monotone -> no livelock.
// h_lds double-buffered ([2][32][256], XOR-swizzled 16B units) -> ONE
// __syncthreads per step. Pointwise directly on MFMA acc registers.
// ---------------------------------------------------------------------------
__global__ void __launch_bounds__(512, 2) k_recur(
        const unsigned short* __restrict__ W2,
        const float* __restrict__ xW2,
        unsigned* __restrict__ hbuf_dw,
        unsigned long long* __restrict__ hsu,      // [63][32][64] u64 history
        float* __restrict__ out_tail) {
    const int nb = blockIdx.x, tid = threadIdx.x;  // nb 0..7
    const int w = tid >> 6, l = tid & 63;
    const int n = l & 15, q = l >> 4;
    const int w7 = w & 3, nt = w >> 2;
    const int bm = nt * 16 + n;                    // this lane's batch (acc col)
    const int a3 = bm & 7;                         // LDS swizzle key

    __shared__ unsigned short h_lds[2][32][Hsz];   // dbuf, row = 512 B, swizzled

    const short8* wp = (const short8*)W2;
    short8 aw_e[2][8], aw_d[2][8];                 // both phases resident
    #pragma unroll
    for (int mt2 = 0; mt2 < 2; ++mt2) {
        const int mtt = 2 * w7 + mt2;
        #pragma unroll
        for (int kt = 0; kt < 8; ++kt) {
            aw_e[mt2][kt] = wp[(((nb * 8 + mtt) * 2 + 0) * 8 + kt) * 64 + l];
            aw_d[mt2][kt] = wp[(((nb * 8 + mtt) * 2 + 1) * 8 + kt) * 64 + l];
        }
    }

    float4 xg[2];
    {
        const float* xb = xW2 + ((long)nb * 512 + tid) * 8;
        xg[0] = ((const float4*)xb)[0];
        xg[1] = ((const float4*)xb)[1];
    }
    float cst[2] = {0.f, 0.f};

    for (int s = 0; s < NSTEP; ++s) {
        // A: stage slot s -> h_lds[s&1]; 4 u64/thread, batched sentinel retry
        {
            const unsigned long long* hp =
                (const unsigned long long*)hbuf_dw + (long)s * 2048;
            char* const ldsb = (char*)&h_lds[s & 1][0][0];
            unsigned long long v[4];
            unsigned pend = 0xFu;
            do {
                #pragma unroll
                for (int i = 0; i < 4; ++i)
                    if (pend & (1u << i))
                        v[i] = __hip_atomic_load(hp + i * 512 + tid, __ATOMIC_RELAXED,
                                                 __HIP_MEMORY_SCOPE_AGENT);
                #pragma unroll
                for (int i = 0; i < 4; ++i)
                    if ((pend & (1u << i)) && !has_sent(v[i])) {
                        int d2 = i * 512 + tid;          // u64 index in slot
                        int b = d2 >> 6, j = d2 & 63;    // row b, 8B unit j
                        *(unsigned long long*)(ldsb + b * 512 +
                            (((j >> 1) ^ (b & 7)) << 4) + (j & 1) * 8) = v[i];
                        pend &= ~(1u << i);
                    }
            } while (__builtin_expect(pend != 0, 0));
        }
        __syncthreads();   // ONLY barrier in the step (dbuf covers the rest)

        // B: MFMA — B operand = h row bm (8 swizzled ds_read_b128), A = regs
        const char* rowb = (const char*)&h_lds[s & 1][bm][0];
        f32x4 acc0 = {0.f,0.f,0.f,0.f}, acc1 = {0.f,0.f,0.f,0.f};
        if (s < Ssz) {
            #pragma unroll
            for (int kt = 0; kt < 8; ++kt) {
                short8 bh = *(const short8*)(rowb + (((4 * kt + q) ^ a3) << 4));
                acc0 = __builtin_amdgcn_mfma_f32_16x16x32_bf16(aw_e[0][kt], bh, acc0, 0, 0, 0);
                acc1 = __builtin_amdgcn_mfma_f32_16x16x32_bf16(aw_e[1][kt], bh, acc1, 0, 0, 0);
            }
        } else {
            #pragma unroll
            for (int kt = 0; kt < 8; ++kt) {
                short8 bh = *(const short8*)(rowb + (((4 * kt + q) ^ a3) << 4));
                acc0 = __builtin_amdgcn_mfma_f32_16x16x32_bf16(aw_d[0][kt], bh, acc0, 0, 0, 0);
                acc1 = __builtin_amdgcn_mfma_f32_16x16x32_bf16(aw_d[1][kt], bh, acc1, 0, 0, 0);
            }
        }

        // C: pointwise on acc regs; shfl-pack 4 cols -> ONE u64 store (q==0)
        #pragma unroll
        for (int mt2 = 0; mt2 < 2; ++mt2) {
            const int mtt = 2 * w7 + mt2;
            const f32x4 a = mt2 ? acc1 : acc0;
            float gi = a[0] + xg[mt2].x;
            float gf = a[1] + xg[mt2].y;
            float gg = a[2] + xg[mt2].z;
            float go = a[3] + xg[mt2].w;
            float c = sigm(gf) * cst[mt2] + sigm(gi) * tanh_fast(gg);
            cst[mt2] = c;
            float h = sigm(go) * tanh_fast(c);

            unsigned pk = f2bf(h);                         // col 4mtt+q (u16)
            unsigned po = (unsigned)__shfl_xor((int)pk, 16);
            unsigned pair = (pk & 0xFFFFu) | (po << 16);   // cols (q, q^1)
            unsigned hi = (unsigned)__shfl_xor((int)pair, 32);
            if (q == 0) {
                unsigned long long u = (unsigned long long)pair
                                     | ((unsigned long long)hi << 32);
                __hip_atomic_store((unsigned long long*)hbuf_dw
                        + (long)(s + 1) * 2048 + bm * 64 + 8 * nb + mtt,
                        u, __ATOMIC_RELAXED, __HIP_MEMORY_SCOPE_AGENT);
                if (s >= Ssz)
                    hsu[((long)(s - Ssz) * Bsz + bm) * 64 + 8 * nb + mtt] = u;
            }
            if (s == NSTEP - 1) {
                const int hc = 32 * nb + 4 * mtt + q;
                out_tail[bm * Hsz + hc]             = h;
                out_tail[Bsz * Hsz + bm * Hsz + hc] = c;
            }
        }

        // D: prefetch next step's x-gates (overlaps next staging/poll)
        {
            const int sn = (s + 1 < NSTEP) ? s + 1 : s;
            const float* xb = xW2 + ((long)sn * 8 + nb) * 4096 + tid * 8;
            xg[0] = ((const float4*)xb)[0];
            xg[1] = ((const float4*)xb)[1];
        }
    }
}

// ---------------------------------------------------------------------------
// K3: projection out[b][td+1][v] = hs[td][b][:] @ Wfc[v][:] + bfc[v]
// grid (125, 9): x = 256-col slice of V, y = group of 7 decoder steps.
// B tile (128KB) staged ONCE per block, reused for 7 steps (r5-verified).
// ---------------------------------------------------------------------------
__global__ void __launch_bounds__(256) k_proj(
        const unsigned short* __restrict__ hs, const unsigned short* __restrict__ WfcB,
        const float* __restrict__ bfc, float* __restrict__ out) {
    const int vb = blockIdx.x;    // 0..124
    const int tid = threadIdx.x, w = tid >> 6, l = tid & 63, n = l & 15, q = l >> 4;

    __shared__ unsigned short a_lds[32][Hsz + 8];     // 16.5 KB
    __shared__ unsigned short b_lds[256][Hsz + 8];    // 132 KB

    {   // stage B tile: 128 KB contiguous from WfcB, remapped into padded rows
        const uint4* g = (const uint4*)(WfcB + (long)vb * 256 * Hsz);
        #pragma unroll 4
        for (int i = 0; i < 32; ++i) {
            int u = i * 256 + tid;           // uint4 index (8 bf16 each)
            int row = u >> 5;
            int kk = (u & 31) * 8;
            *(uint4*)&b_lds[row][kk] = g[u];
        }
    }

    for (int tdi = 0; tdi < 7; ++tdi) {
        const int td = blockIdx.y * 7 + tdi;
        if (tdi > 0) __syncthreads();   // previous iteration's a_lds reads done
        {   // stage A: hs rows for this td (contiguous 16 KB)
            int b = tid >> 3, seg = tid & 7;
            const uint4* g = (const uint4*)(hs + ((long)td * Bsz + b) * Hsz);
            #pragma unroll
            for (int i = 0; i < 4; ++i)
                *(uint4*)&a_lds[b][i * 64 + seg * 8] = g[i * 8 + seg];
        }
        __syncthreads();                 // A (and, first iter, B) staged

        short8 af[2][8];
        #pragma unroll
        for (int kt = 0; kt < 8; ++kt) {
            int k0 = kt * 32 + q * 8;
            af[0][kt] = *(const short8*)&a_lds[n][k0];
            af[1][kt] = *(const short8*)&a_lds[16 + n][k0];
        }
        f32x4 acc[2][4];
        #pragma unroll
        for (int nt = 0; nt < 4; ++nt) {
            acc[0][nt] = (f32x4){0.f,0.f,0.f,0.f};
            acc[1][nt] = (f32x4){0.f,0.f,0.f,0.f};
        }
        #pragma unroll
        for (int nt = 0; nt < 4; ++nt) {
            int cl = w * 64 + nt * 16 + n;
            #pragma unroll
            for (int kt = 0; kt < 8; ++kt) {
                short8 bf = *(const short8*)&b_lds[cl][kt * 32 + q * 8];
                acc[0][nt] = __builtin_amdgcn_mfma_f32_16x16x32_bf16(af[0][kt], bf, acc[0][nt], 0, 0, 0);
                acc[1][nt] = __builtin_amdgcn_mfma_f32_16x16x32_bf16(af[1][kt], bf, acc[1][nt], 0, 0, 0);
            }
        }
        #pragma unroll
        for (int nt = 0; nt < 4; ++nt) {
            int col = vb * 256 + w * 64 + nt * 16 + n;
            float bv = bfc[col];
            #pragma unroll
            for (int mt = 0; mt < 2; ++mt) {
                #pragma unroll
                for (int r = 0; r < 4; ++r) {
                    int b = mt * 16 + q * 4 + r;
                    out[(long)b * (Tsz * Vsz) + (long)(td + 1) * Vsz + col] = acc[mt][nt][r] + bv;
                }
            }
        }
    }
}

// ---------------------------------------------------------------------------
// K4: zero prediction slot t=0 (d_out is poisoned before every launch)
// ---------------------------------------------------------------------------
__global__ void k_zero0(float* __restrict__ out) {
    int i = blockIdx.x * 256 + threadIdx.x;    // 256000 float4s = 32*32000 floats
    int b = i / 8000;
    int c = i % 8000;
    ((float4*)(out + (long)b * (Tsz * Vsz)))[c] = make_float4(0.f, 0.f, 0.f, 0.f);
}

// ---------------------------------------------------------------------------
extern "C" void kernel_launch(void* const* d_in, const int* in_sizes, int n_in,
                              void* d_out, int out_size, void* d_ws, size_t ws_size,
                              hipStream_t stream) {
    const int*   src     = (const int*)d_in[0];
    const int*   trg     = (const int*)d_in[1];
    const float* emb_src = (const float*)d_in[2];
    const float* Wih_e   = (const float*)d_in[3];
    const float* Whh_e   = (const float*)d_in[4];
    const float* b_e     = (const float*)d_in[5];
    const float* emb_trg = (const float*)d_in[6];
    const float* Wih_d   = (const float*)d_in[7];
    const float* Whh_d   = (const float*)d_in[8];
    const float* b_d     = (const float*)d_in[9];
    const float* Wfc     = (const float*)d_in[10];
    const float* bfc     = (const float*)d_in[11];
    float* out = (float*)d_out;

    char* ws = (char*)d_ws;
    float*          xW2  = (float*)ws;                          // 191*32768*4 = 25,034,752 B
    unsigned short* WfcB = (unsigned short*)(ws + 25034752);    // 32000*256*2 = 16,384,000 B
    unsigned short* hs   = (unsigned short*)(ws + 41418752);    // 63*32*256*2 =  1,032,192 B
    unsigned short* W2   = (unsigned short*)(ws + 42450944);    // packed Whh  =  1,048,576 B
    unsigned*       hbuf = (unsigned*)(ws + 43499520);          // 192 slots x 16 KB = 3,145,728 B
    (void)ws_size;

    k_cvt<<<4000, 256, 0, stream>>>(Wfc, WfcB, 8192000L);
    k_pack<<<256, 256, 0, stream>>>(Whh_e, Whh_d, W2);
    k_input<<<dim3(16, 191), 256, 0, stream>>>(src, trg, emb_src, emb_trg,
                                               Wih_e, Wih_d, b_e, b_d, xW2, hbuf);
    k_recur<<<NB, 512, 0, stream>>>(W2, xW2, hbuf,
                                    (unsigned long long*)hs, out + 65536000L);
    k_zero0<<<1000, 256, 0, stream>>>(out);
    k_proj<<<dim3(125, 9), 256, 0, stream>>>(hs, WfcB, bfc, out);
}